// Round 3
// baseline (199.035 us; speedup 1.0000x reference)
//
#include <hip/hip_runtime.h>
#include <hip/hip_bf16.h>

#define NB 4
#define SS 1024
#define DIN 768
#define NH 12
#define DH 64

typedef float f32x4 __attribute__((ext_vector_type(4)));
typedef short bf16x8 __attribute__((ext_vector_type(8)));

static __device__ __forceinline__ unsigned short f2bf(float f) {
    __hip_bfloat16 h = __float2bfloat16(f);
    return *reinterpret_cast<unsigned short*>(&h);
}

static __device__ __forceinline__ float exp2_fast(float x) {
    return __builtin_amdgcn_exp2f(x);   // v_exp_f32: computes 2^x
}

static __device__ __forceinline__ void gload16(const void* g, void* l) {
    __builtin_amdgcn_global_load_lds(
        (const __attribute__((address_space(1))) void*)g,
        (__attribute__((address_space(3))) void*)l, 16, 0, 0);
}

// ---------------- kernel 1: cast x (f32) -> xb (bf16), [4096][768] ----------------
__global__ void cast_x_kernel(const float* __restrict__ x, unsigned short* __restrict__ xb) {
    int i = (blockIdx.x * 256 + threadIdx.x) * 4;
    float4 v = *reinterpret_cast<const float4*>(x + i);
    ushort4 o;
    o.x = f2bf(v.x); o.y = f2bf(v.y); o.z = f2bf(v.z); o.w = f2bf(v.w);
    *reinterpret_cast<ushort4*>(xb + i) = o;
}

// ------------- kernel 2: W [H][DIN][DH] f32 -> wt [3][H][DH][DIN] bf16 -------------
__global__ void transpose_w_kernel(const float* __restrict__ Wq, const float* __restrict__ Wk,
                                   const float* __restrict__ Wv, unsigned short* __restrict__ wt) {
    __shared__ float lds[64][68];
    int d0 = blockIdx.x * 64;
    int h  = blockIdx.y;
    int p  = blockIdx.z;
    const float* W = (p == 0) ? Wq : (p == 1) ? Wk : Wv;
    const float* base = W + (size_t)h * DIN * DH;   // [768][64]
    int tid = threadIdx.x;
    int rr = tid >> 4, c4 = tid & 15;
#pragma unroll
    for (int i = 0; i < 4; ++i) {
        int d = i * 16 + rr;
        float4 v = *reinterpret_cast<const float4*>(base + (size_t)(d0 + d) * DH + c4 * 4);
        lds[d][c4 * 4 + 0] = v.x; lds[d][c4 * 4 + 1] = v.y;
        lds[d][c4 * 4 + 2] = v.z; lds[d][c4 * 4 + 3] = v.w;
    }
    __syncthreads();
    unsigned short* outp = wt + ((size_t)(p * NH + h) * DH) * DIN;
#pragma unroll
    for (int i = 0; i < 4; ++i) {
        int e = i * 16 + rr;
        int dc = c4 * 4;
        ushort4 o;
        o.x = f2bf(lds[dc + 0][e]); o.y = f2bf(lds[dc + 1][e]);
        o.z = f2bf(lds[dc + 2][e]); o.w = f2bf(lds[dc + 3][e]);
        *reinterpret_cast<ushort4*>(outp + (size_t)e * DIN + d0 + dc) = o;
    }
}

// ---- kernel 3: QKV GEMM, m97 structure. A = xb [4096][768], B^T = wt [2304][768].
// ---- 128x128 tile, BK=64, 4 waves (2x2), global_load_lds w16, linear LDS.
__global__ __launch_bounds__(256) void qkv_gemm_kernel(
    const unsigned short* __restrict__ xb, const unsigned short* __restrict__ wt,
    unsigned short* __restrict__ qb, unsigned short* __restrict__ kb,
    unsigned short* __restrict__ vT) {
    __shared__ __align__(16) unsigned char smem[32768];
    unsigned short* a_lds = (unsigned short*)smem;            // [128][64] linear
    unsigned short* b_lds = (unsigned short*)(smem + 16384);  // [128][64] linear

    int m0 = blockIdx.x * 128;
    int n0 = blockIdx.y * 128;
    int tid = threadIdx.x, lane = tid & 63, w = tid >> 6;
    int l15 = lane & 15, hi4 = (lane >> 4) * 4, hi8 = (lane >> 4) * 8;
    int wr = w >> 1, wc = w & 1;

    f32x4 acc[4][4] = {};

    // staging: thread covers row = i*32 + w*8 + (lane>>3), col = (lane&7)*8, 16B each
    const unsigned short* ab = xb + (size_t)(m0 + w * 8 + (lane >> 3)) * DIN + (lane & 7) * 8;
    const unsigned short* bb = wt + (size_t)(n0 + w * 8 + (lane >> 3)) * DIN + (lane & 7) * 8;
    unsigned short* al = a_lds + w * 512 + lane * 8;
    unsigned short* bl = b_lds + w * 512 + lane * 8;

    for (int k0 = 0; k0 < DIN; k0 += 64) {
        __syncthreads();
#pragma unroll
        for (int i = 0; i < 4; ++i) gload16(ab + (size_t)(i * 32) * DIN + k0, al + i * 2048);
#pragma unroll
        for (int i = 0; i < 4; ++i) gload16(bb + (size_t)(i * 32) * DIN + k0, bl + i * 2048);
        __syncthreads();
#pragma unroll
        for (int kk = 0; kk < 64; kk += 32) {
            bf16x8 af[4], bf[4];
#pragma unroll
            for (int m = 0; m < 4; ++m)
                af[m] = *reinterpret_cast<const bf16x8*>(a_lds + (wr * 64 + m * 16 + l15) * 64 + kk + hi8);
#pragma unroll
            for (int n = 0; n < 4; ++n)
                bf[n] = *reinterpret_cast<const bf16x8*>(b_lds + (wc * 64 + n * 16 + l15) * 64 + kk + hi8);
#pragma unroll
            for (int m = 0; m < 4; ++m)
#pragma unroll
                for (int n = 0; n < 4; ++n)
                    acc[m][n] = __builtin_amdgcn_mfma_f32_16x16x32_bf16(af[m], bf[n], acc[m][n], 0, 0, 0);
        }
    }
    __syncthreads();   // all MFMA reads of a/b LDS done before scratch reuse

    int p = n0 / 768;                      // whole block is one projection
    int h = ((n0 % 768) >> 6) + wc;        // wave's 64-col slab -> head
    int b = m0 >> 10;
    int s_base = (m0 & 1023) + wr * 64;

    if (p < 2) {
        // Q gets 0.125 * log2(e) folded in so attention softmax runs in exp2 space
        float qs = (p == 0) ? 0.180336880f : 1.0f;
        unsigned short* dst = ((p == 0) ? qb : kb) + ((size_t)(b * NH + h) * SS + s_base) * DH;
#pragma unroll
        for (int m = 0; m < 4; ++m)
#pragma unroll
            for (int n = 0; n < 4; ++n)
#pragma unroll
                for (int r = 0; r < 4; ++r)
                    dst[(size_t)(m * 16 + hi4 + r) * DH + n * 16 + l15] = f2bf(acc[m][n][r] * qs);
    } else {
        // V: per-wave 16x68 f32 strip transpose (wave-private, no barrier needed)
        float* sc = (float*)smem + w * 1088;
        unsigned short* dst = vT + ((size_t)(b * NH + h) * DH + lane) * SS + s_base;
#pragma unroll
        for (int m = 0; m < 4; ++m) {
#pragma unroll
            for (int n = 0; n < 4; ++n)
#pragma unroll
                for (int r = 0; r < 4; ++r)
                    sc[(hi4 + r) * 68 + n * 16 + l15] = acc[m][n][r];
            unsigned short vv[16];
#pragma unroll
            for (int t = 0; t < 16; ++t) vv[t] = f2bf(sc[t * 68 + lane]);
            *reinterpret_cast<uint4*>(dst + m * 16)     = *reinterpret_cast<const uint4*>(vv);
            *reinterpret_cast<uint4*>(dst + m * 16 + 8) = *reinterpret_cast<const uint4*>(vv + 8);
        }
    }
}

// ---- kernel 4: causal flash attention, no K/V staging (L2-resident), no barriers.
template<bool DIAG>
static __device__ __forceinline__ void attn_step(
    int kv, int row_q, int l15, int hi4, int hi8,
    const unsigned short* kg, const unsigned short* vg,
    bf16x8 qf0, bf16x8 qf1, unsigned short* pw,
    float m_r[4], float l_r[4], f32x4 o_acc[4]) {
    bf16x8 kf[2][4];
#pragma unroll
    for (int s = 0; s < 2; ++s)
#pragma unroll
        for (int n = 0; n < 4; ++n)
            kf[s][n] = *reinterpret_cast<const bf16x8*>(
                kg + (size_t)(kv * 64 + 16 * n + l15) * DH + 32 * s + hi8);
    f32x4 sacc[4] = {};
#pragma unroll
    for (int n = 0; n < 4; ++n) {
        sacc[n] = __builtin_amdgcn_mfma_f32_16x16x32_bf16(qf0, kf[0][n], sacc[n], 0, 0, 0);
        sacc[n] = __builtin_amdgcn_mfma_f32_16x16x32_bf16(qf1, kf[1][n], sacc[n], 0, 0, 0);
    }
    float pv[4][4];
#pragma unroll
    for (int n = 0; n < 4; ++n)
#pragma unroll
        for (int r = 0; r < 4; ++r) {
            float sv = sacc[n][r];
            if (DIAG && (kv * 64 + 16 * n + l15) > (row_q + hi4 + r)) sv = -INFINITY;
            pv[n][r] = sv;
        }
#pragma unroll
    for (int r = 0; r < 4; ++r) {
        float mx = fmaxf(fmaxf(pv[0][r], pv[1][r]), fmaxf(pv[2][r], pv[3][r]));
        mx = fmaxf(mx, __shfl_xor(mx, 1));
        mx = fmaxf(mx, __shfl_xor(mx, 2));
        mx = fmaxf(mx, __shfl_xor(mx, 4));
        mx = fmaxf(mx, __shfl_xor(mx, 8));
        float m_new = fmaxf(m_r[r], mx);
        float s0 = exp2_fast(pv[0][r] - m_new);
        float s1 = exp2_fast(pv[1][r] - m_new);
        float s2 = exp2_fast(pv[2][r] - m_new);
        float s3 = exp2_fast(pv[3][r] - m_new);
        pv[0][r] = s0; pv[1][r] = s1; pv[2][r] = s2; pv[3][r] = s3;
        float sum = (s0 + s1) + (s2 + s3);
        sum += __shfl_xor(sum, 1);
        sum += __shfl_xor(sum, 2);
        sum += __shfl_xor(sum, 4);
        sum += __shfl_xor(sum, 8);
        float alpha = exp2_fast(m_r[r] - m_new);
        l_r[r] = l_r[r] * alpha + sum;
        m_r[r] = m_new;
#pragma unroll
        for (int n = 0; n < 4; ++n) o_acc[n][r] *= alpha;
    }
    // P -> bf16 via wave-private LDS (C/D layout -> A-frag layout)
#pragma unroll
    for (int n = 0; n < 4; ++n)
#pragma unroll
        for (int r = 0; r < 4; ++r)
            pw[(hi4 + r) * 72 + 16 * n + l15] = f2bf(pv[n][r]);
    bf16x8 pa0 = *reinterpret_cast<const bf16x8*>(pw + l15 * 72 + hi8);
    bf16x8 pa1 = *reinterpret_cast<const bf16x8*>(pw + l15 * 72 + 32 + hi8);
#pragma unroll
    for (int n = 0; n < 4; ++n) {
        bf16x8 vf0 = *reinterpret_cast<const bf16x8*>(
            vg + (size_t)(16 * n + l15) * SS + kv * 64 + hi8);
        bf16x8 vf1 = *reinterpret_cast<const bf16x8*>(
            vg + (size_t)(16 * n + l15) * SS + kv * 64 + 32 + hi8);
        o_acc[n] = __builtin_amdgcn_mfma_f32_16x16x32_bf16(pa0, vf0, o_acc[n], 0, 0, 0);
        o_acc[n] = __builtin_amdgcn_mfma_f32_16x16x32_bf16(pa1, vf1, o_acc[n], 0, 0, 0);
    }
}

__global__ __launch_bounds__(256) void attn_kernel(
    const unsigned short* __restrict__ qb, const unsigned short* __restrict__ kb,
    const unsigned short* __restrict__ vT, float* __restrict__ out) {
    __shared__ __align__(16) unsigned short p_lds[4 * 16 * 72];
    int qi = blockIdx.x, h = blockIdx.y, b = blockIdx.z;
    int q0 = qi * 64;
    int tid = threadIdx.x, lane = tid & 63, w = tid >> 6;
    int l15 = lane & 15, hi4 = (lane >> 4) * 4, hi8 = (lane >> 4) * 8;
    size_t bh = (size_t)(b * NH + h);

    const unsigned short* qp = qb + (bh * SS + q0 + 16 * w + l15) * DH;
    bf16x8 qf0 = *reinterpret_cast<const bf16x8*>(qp + hi8);
    bf16x8 qf1 = *reinterpret_cast<const bf16x8*>(qp + 32 + hi8);
    const unsigned short* kg = kb + bh * SS * DH;
    const unsigned short* vg = vT + bh * DH * SS;
    unsigned short* pw = p_lds + w * 16 * 72;

    float m_r[4] = {-INFINITY, -INFINITY, -INFINITY, -INFINITY};
    float l_r[4] = {0.f, 0.f, 0.f, 0.f};
    f32x4 o_acc[4] = {};
    int row_q = q0 + 16 * w;

    for (int kv = 0; kv < qi; ++kv)
        attn_step<false>(kv, row_q, l15, hi4, hi8, kg, vg, qf0, qf1, pw, m_r, l_r, o_acc);
    attn_step<true>(qi, row_q, l15, hi4, hi8, kg, vg, qf0, qf1, pw, m_r, l_r, o_acc);

    float inv[4];
#pragma unroll
    for (int r = 0; r < 4; ++r) inv[r] = 1.f / l_r[r];
#pragma unroll
    for (int n = 0; n < 4; ++n)
#pragma unroll
        for (int r = 0; r < 4; ++r) {
            int q = q0 + 16 * w + hi4 + r;
            int e = 16 * n + l15;
            out[((size_t)b * SS + q) * (NH * DH) + h * DH + e] = o_acc[n][r] * inv[r];
        }
}

extern "C" void kernel_launch(void* const* d_in, const int* in_sizes, int n_in,
                              void* d_out, int out_size, void* d_ws, size_t ws_size,
                              hipStream_t stream) {
    const float* x  = (const float*)d_in[0];
    const float* Wq = (const float*)d_in[1];
    const float* Wk = (const float*)d_in[2];
    const float* Wv = (const float*)d_in[3];
    float* out = (float*)d_out;

    char* ws = (char*)d_ws;
    unsigned short* xb = (unsigned short*)ws;                   //  6,291,456 B
    unsigned short* wt = (unsigned short*)(ws +  6291456);      //  3,538,944 B
    unsigned short* qb = (unsigned short*)(ws +  9830400);      //  6,291,456 B
    unsigned short* kb = (unsigned short*)(ws + 16121856);      //  6,291,456 B
    unsigned short* vT = (unsigned short*)(ws + 22413312);      //  6,291,456 B

    hipLaunchKernelGGL(cast_x_kernel,      dim3(3072),      dim3(256), 0, stream, x, xb);
    hipLaunchKernelGGL(transpose_w_kernel, dim3(12, 12, 3), dim3(256), 0, stream, Wq, Wk, Wv, wt);
    hipLaunchKernelGGL(qkv_gemm_kernel,    dim3(32, 18),    dim3(256), 0, stream, xb, wt, qb, kb, vT);
    hipLaunchKernelGGL(attn_kernel,        dim3(16, 12, 4), dim3(256), 0, stream, qb, kb, vT, out);
}

// Round 4
// 124.750 us; speedup vs baseline: 1.5955x; 1.5955x over previous
//
#include <hip/hip_runtime.h>
#include <hip/hip_bf16.h>

#define NB 4
#define SS 1024
#define DIN 768
#define NH 12
#define DH 64

typedef float f32x4 __attribute__((ext_vector_type(4)));
typedef short bf16x8 __attribute__((ext_vector_type(8)));

static __device__ __forceinline__ unsigned short f2bf(float f) {
    __hip_bfloat16 h = __float2bfloat16(f);
    return *reinterpret_cast<unsigned short*>(&h);
}

static __device__ __forceinline__ float exp2_fast(float x) {
    return __builtin_amdgcn_exp2f(x);   // v_exp_f32: 2^x
}

static __device__ __forceinline__ void gload16(const void* g, void* l) {
    __builtin_amdgcn_global_load_lds(
        (const __attribute__((address_space(1))) void*)g,
        (__attribute__((address_space(3))) void*)l, 16, 0, 0);
}

// ---------------- kernel 1: cast x (f32) -> xb (bf16), [4096][768] ----------------
__global__ void cast_x_kernel(const float* __restrict__ x, unsigned short* __restrict__ xb) {
    int i = (blockIdx.x * 256 + threadIdx.x) * 4;
    float4 v = *reinterpret_cast<const float4*>(x + i);
    ushort4 o;
    o.x = f2bf(v.x); o.y = f2bf(v.y); o.z = f2bf(v.z); o.w = f2bf(v.w);
    *reinterpret_cast<ushort4*>(xb + i) = o;
}

// ------------- kernel 2: W [H][DIN][DH] f32 -> wt [3][H][DH][DIN] bf16 -------------
__global__ void transpose_w_kernel(const float* __restrict__ Wq, const float* __restrict__ Wk,
                                   const float* __restrict__ Wv, unsigned short* __restrict__ wt) {
    __shared__ float lds[64][68];
    int d0 = blockIdx.x * 64;
    int h  = blockIdx.y;
    int p  = blockIdx.z;
    const float* W = (p == 0) ? Wq : (p == 1) ? Wk : Wv;
    const float* base = W + (size_t)h * DIN * DH;   // [768][64]
    int tid = threadIdx.x;
    int rr = tid >> 4, c4 = tid & 15;
#pragma unroll
    for (int i = 0; i < 4; ++i) {
        int d = i * 16 + rr;
        float4 v = *reinterpret_cast<const float4*>(base + (size_t)(d0 + d) * DH + c4 * 4);
        lds[d][c4 * 4 + 0] = v.x; lds[d][c4 * 4 + 1] = v.y;
        lds[d][c4 * 4 + 2] = v.z; lds[d][c4 * 4 + 3] = v.w;
    }
    __syncthreads();
    unsigned short* outp = wt + ((size_t)(p * NH + h) * DH) * DIN;
#pragma unroll
    for (int i = 0; i < 4; ++i) {
        int e = i * 16 + rr;
        int dc = c4 * 4;
        ushort4 o;
        o.x = f2bf(lds[dc + 0][e]); o.y = f2bf(lds[dc + 1][e]);
        o.z = f2bf(lds[dc + 2][e]); o.w = f2bf(lds[dc + 3][e]);
        *reinterpret_cast<ushort4*>(outp + (size_t)e * DIN + d0 + dc) = o;
    }
}

// ---- kernel 3: QKV GEMM. A = xb [4096][768], B^T = wt [2304][768]. Tile 128x96
// ---- (grid 32x24 = 768 blocks = 3/CU exact). gload_lds w16 with pre-swizzled
// ---- source (T2/m173: XOR byte ^ ((row&7)<<4)), swizzled ds_read -> 2-way max.
__global__ __launch_bounds__(256) void qkv_gemm_kernel(
    const unsigned short* __restrict__ xb, const unsigned short* __restrict__ wt,
    unsigned short* __restrict__ qb, unsigned short* __restrict__ kb,
    unsigned short* __restrict__ vT) {
    __shared__ __align__(16) unsigned char smem[28672];
    unsigned short* a_lds = (unsigned short*)smem;            // [128][64] swizzled
    unsigned short* b_lds = (unsigned short*)(smem + 16384);  // [96][64]  swizzled

    int m0 = blockIdx.x * 128;
    int n0 = blockIdx.y * 96;
    int tid = threadIdx.x, lane = tid & 63, w = tid >> 6;
    int l15 = lane & 15, hi4 = (lane >> 4) * 4, hi8 = (lane >> 4) * 8;
    int wr = w >> 1, wc = w & 1;
    int srow = tid >> 3;            // 0..31
    int scolb = (tid & 7) * 16;     // byte col {0,16,...,112}
    int sw = (l15 & 7) << 4;        // read-side XOR

    f32x4 acc[4][3] = {};

    for (int k0 = 0; k0 < DIN; k0 += 64) {
        __syncthreads();
#pragma unroll
        for (int i = 0; i < 4; ++i) {
            int row = i * 32 + srow;
            int cb = scolb ^ ((row & 7) << 4);
            gload16(xb + (size_t)(m0 + row) * DIN + k0 + (cb >> 1), a_lds + row * 64 + (scolb >> 1));
        }
#pragma unroll
        for (int i = 0; i < 3; ++i) {
            int row = i * 32 + srow;
            int cb = scolb ^ ((row & 7) << 4);
            gload16(wt + (size_t)(n0 + row) * DIN + k0 + (cb >> 1), b_lds + row * 64 + (scolb >> 1));
        }
        __syncthreads();
#pragma unroll
        for (int kk = 0; kk < 64; kk += 32) {
            int cb = ((kk + hi8) * 2) ^ sw;
            bf16x8 af[4], bfr[3];
#pragma unroll
            for (int m = 0; m < 4; ++m)
                af[m] = *reinterpret_cast<const bf16x8*>(a_lds + (wr * 64 + m * 16 + l15) * 64 + (cb >> 1));
#pragma unroll
            for (int n = 0; n < 3; ++n)
                bfr[n] = *reinterpret_cast<const bf16x8*>(b_lds + (wc * 48 + n * 16 + l15) * 64 + (cb >> 1));
#pragma unroll
            for (int m = 0; m < 4; ++m)
#pragma unroll
                for (int n = 0; n < 3; ++n)
                    acc[m][n] = __builtin_amdgcn_mfma_f32_16x16x32_bf16(af[m], bfr[n], acc[m][n], 0, 0, 0);
        }
    }
    __syncthreads();   // before LDS scratch reuse

    int p  = n0 / 768;
    int cp = (n0 % 768) + wc * 48;         // col base within projection
    int b  = m0 >> 10;
    int s_base = (m0 & 1023) + wr * 64;

    if (p < 2) {
        float qs = (p == 0) ? 0.180336880f : 1.0f;   // 0.125 * log2(e) folded into Q
        unsigned short* dstb = (p == 0) ? qb : kb;
#pragma unroll
        for (int m = 0; m < 4; ++m)
#pragma unroll
            for (int n = 0; n < 3; ++n)
#pragma unroll
                for (int r = 0; r < 4; ++r) {
                    int col = cp + n * 16 + l15;
                    int h = col >> 6, e = col & 63;
                    dstb[((size_t)(b * NH + h) * SS + s_base + m * 16 + hi4 + r) * DH + e] =
                        f2bf(acc[m][n][r] * qs);
                }
    } else {
        // V: per-wave 16x49 f32 strip transpose, store [b][h][e][t]
        float* sc = (float*)smem + w * 784;
#pragma unroll
        for (int m = 0; m < 4; ++m) {
#pragma unroll
            for (int n = 0; n < 3; ++n)
#pragma unroll
                for (int r = 0; r < 4; ++r)
                    sc[(hi4 + r) * 49 + n * 16 + l15] = acc[m][n][r];
            if (lane < 48) {
                unsigned short vv[16];
#pragma unroll
                for (int t = 0; t < 16; ++t) vv[t] = f2bf(sc[t * 49 + lane]);
                int col = cp + lane;
                int h = col >> 6, e = col & 63;
                unsigned short* dst = vT + ((size_t)(b * NH + h) * DH + e) * SS + s_base + m * 16;
                *reinterpret_cast<uint4*>(dst)     = *reinterpret_cast<const uint4*>(vv);
                *reinterpret_cast<uint4*>(dst + 8) = *reinterpret_cast<const uint4*>(vv + 8);
            }
        }
    }
}

// ---- kernel 4: causal flash attention, LDS double-buffered 2-phase, swizzled.
struct AttnCtx {
    const unsigned short* kg;
    const unsigned short* vg;
    unsigned short* k0lds; unsigned short* k1lds;
    unsigned short* v0lds; unsigned short* v1lds;
    unsigned short* pw;
    int srow, scolb, l15, hi4, hi8, sw;
};

static __device__ __forceinline__ void attn_stage(const AttnCtx& c, int buf, int kv) {
    unsigned short* kl = buf ? c.k1lds : c.k0lds;
    unsigned short* vl = buf ? c.v1lds : c.v0lds;
#pragma unroll
    for (int i = 0; i < 2; ++i) {
        int row = i * 32 + c.srow;
        int cb = c.scolb ^ ((row & 7) << 4);
        gload16(c.kg + (size_t)(kv * 64 + row) * DH + (cb >> 1), kl + row * 64 + (c.scolb >> 1));
        gload16(c.vg + (size_t)row * SS + kv * 64 + (cb >> 1),   vl + row * 64 + (c.scolb >> 1));
    }
}

template<bool DIAG>
static __device__ __forceinline__ void attn_step(
    const AttnCtx& c, int buf, int kv, int row_q,
    bf16x8 qf0, bf16x8 qf1, float m_r[4], float l_r[4], f32x4 o_acc[4]) {
    const unsigned short* kl = buf ? c.k1lds : c.k0lds;
    const unsigned short* vl = buf ? c.v1lds : c.v0lds;
    int l15 = c.l15, hi4 = c.hi4, hi8 = c.hi8, sw = c.sw;

    f32x4 sacc[4] = {};
#pragma unroll
    for (int s = 0; s < 2; ++s) {
        int cb = ((32 * s + hi8) * 2) ^ sw;
#pragma unroll
        for (int n = 0; n < 4; ++n) {
            bf16x8 kf = *reinterpret_cast<const bf16x8*>(kl + (16 * n + l15) * 64 + (cb >> 1));
            sacc[n] = __builtin_amdgcn_mfma_f32_16x16x32_bf16(s == 0 ? qf0 : qf1, kf, sacc[n], 0, 0, 0);
        }
    }
    float pv[4][4];
#pragma unroll
    for (int n = 0; n < 4; ++n)
#pragma unroll
        for (int r = 0; r < 4; ++r) {
            float sv = sacc[n][r];
            if (DIAG && (kv * 64 + 16 * n + l15) > (row_q + hi4 + r)) sv = -INFINITY;
            pv[n][r] = sv;
        }
#pragma unroll
    for (int r = 0; r < 4; ++r) {
        float mx = fmaxf(fmaxf(pv[0][r], pv[1][r]), fmaxf(pv[2][r], pv[3][r]));
        mx = fmaxf(mx, __shfl_xor(mx, 1));
        mx = fmaxf(mx, __shfl_xor(mx, 2));
        mx = fmaxf(mx, __shfl_xor(mx, 4));
        mx = fmaxf(mx, __shfl_xor(mx, 8));
        float m_new = fmaxf(m_r[r], mx);
        float s0 = exp2_fast(pv[0][r] - m_new);
        float s1 = exp2_fast(pv[1][r] - m_new);
        float s2 = exp2_fast(pv[2][r] - m_new);
        float s3 = exp2_fast(pv[3][r] - m_new);
        pv[0][r] = s0; pv[1][r] = s1; pv[2][r] = s2; pv[3][r] = s3;
        float sum = (s0 + s1) + (s2 + s3);
        sum += __shfl_xor(sum, 1);
        sum += __shfl_xor(sum, 2);
        sum += __shfl_xor(sum, 4);
        sum += __shfl_xor(sum, 8);
        float alpha = exp2_fast(m_r[r] - m_new);
        l_r[r] = l_r[r] * alpha + sum;
        m_r[r] = m_new;
#pragma unroll
        for (int n = 0; n < 4; ++n) o_acc[n][r] *= alpha;
    }
    // P -> bf16 via wave-private LDS strip (stride 72 shorts: conflict-free-ish)
#pragma unroll
    for (int n = 0; n < 4; ++n)
#pragma unroll
        for (int r = 0; r < 4; ++r)
            c.pw[(hi4 + r) * 72 + 16 * n + l15] = f2bf(pv[n][r]);
    bf16x8 pa0 = *reinterpret_cast<const bf16x8*>(c.pw + l15 * 72 + hi8);
    bf16x8 pa1 = *reinterpret_cast<const bf16x8*>(c.pw + l15 * 72 + 32 + hi8);
#pragma unroll
    for (int s = 0; s < 2; ++s) {
        int cb = ((32 * s + hi8) * 2) ^ sw;
#pragma unroll
        for (int n = 0; n < 4; ++n) {
            bf16x8 vf = *reinterpret_cast<const bf16x8*>(vl + (16 * n + l15) * 64 + (cb >> 1));
            o_acc[n] = __builtin_amdgcn_mfma_f32_16x16x32_bf16(s == 0 ? pa0 : pa1, vf, o_acc[n], 0, 0, 0);
        }
    }
}

__global__ __launch_bounds__(256) void attn_kernel(
    const unsigned short* __restrict__ qb, const unsigned short* __restrict__ kb,
    const unsigned short* __restrict__ vT, float* __restrict__ out) {
    __shared__ __align__(16) unsigned short k_lds[2][64 * 64];
    __shared__ __align__(16) unsigned short v_lds[2][64 * 64];
    __shared__ __align__(16) unsigned short p_lds[4 * 16 * 72];

    // load-balanced decode: long blocks (qi=15) first
    int bid = blockIdx.x;
    int qi = 15 - bid / 48;
    int rem = bid % 48;
    int h = rem % 12, b = rem / 12;
    int q0 = qi * 64;
    int tid = threadIdx.x, lane = tid & 63, w = tid >> 6;
    int l15 = lane & 15, hi4 = (lane >> 4) * 4, hi8 = (lane >> 4) * 8;
    size_t bh = (size_t)(b * NH + h);

    AttnCtx c;
    c.kg = kb + bh * SS * DH;
    c.vg = vT + bh * DH * SS;
    c.k0lds = k_lds[0]; c.k1lds = k_lds[1];
    c.v0lds = v_lds[0]; c.v1lds = v_lds[1];
    c.pw = p_lds + w * 16 * 72;
    c.srow = tid >> 3; c.scolb = (tid & 7) * 16;
    c.l15 = l15; c.hi4 = hi4; c.hi8 = hi8; c.sw = (l15 & 7) << 4;

    const unsigned short* qp = qb + (bh * SS + q0 + 16 * w + l15) * DH;
    bf16x8 qf0 = *reinterpret_cast<const bf16x8*>(qp + hi8);
    bf16x8 qf1 = *reinterpret_cast<const bf16x8*>(qp + 32 + hi8);

    float m_r[4] = {-INFINITY, -INFINITY, -INFINITY, -INFINITY};
    float l_r[4] = {0.f, 0.f, 0.f, 0.f};
    f32x4 o_acc[4] = {};
    int row_q = q0 + 16 * w;

    attn_stage(c, 0, 0);
    __syncthreads();
    for (int kv = 0; kv < qi; ++kv) {
        int cur = kv & 1;
        attn_stage(c, cur ^ 1, kv + 1);            // overlap next-tile DMA with compute
        attn_step<false>(c, cur, kv, row_q, qf0, qf1, m_r, l_r, o_acc);
        __syncthreads();                            // drains vmcnt + lgkmcnt
    }
    attn_step<true>(c, qi & 1, qi, row_q, qf0, qf1, m_r, l_r, o_acc);

    float inv[4];
#pragma unroll
    for (int r = 0; r < 4; ++r) inv[r] = 1.f / l_r[r];
#pragma unroll
    for (int n = 0; n < 4; ++n)
#pragma unroll
        for (int r = 0; r < 4; ++r) {
            int q = q0 + 16 * w + hi4 + r;
            int e = 16 * n + l15;
            out[((size_t)b * SS + q) * (NH * DH) + h * DH + e] = o_acc[n][r] * inv[r];
        }
}

extern "C" void kernel_launch(void* const* d_in, const int* in_sizes, int n_in,
                              void* d_out, int out_size, void* d_ws, size_t ws_size,
                              hipStream_t stream) {
    const float* x  = (const float*)d_in[0];
    const float* Wq = (const float*)d_in[1];
    const float* Wk = (const float*)d_in[2];
    const float* Wv = (const float*)d_in[3];
    float* out = (float*)d_out;

    char* ws = (char*)d_ws;
    unsigned short* xb = (unsigned short*)ws;                   //  6,291,456 B
    unsigned short* wt = (unsigned short*)(ws +  6291456);      //  3,538,944 B
    unsigned short* qb = (unsigned short*)(ws +  9830400);      //  6,291,456 B
    unsigned short* kb = (unsigned short*)(ws + 16121856);      //  6,291,456 B
    unsigned short* vT = (unsigned short*)(ws + 22413312);      //  6,291,456 B

    hipLaunchKernelGGL(cast_x_kernel,      dim3(3072),      dim3(256), 0, stream, x, xb);
    hipLaunchKernelGGL(transpose_w_kernel, dim3(12, 12, 3), dim3(256), 0, stream, Wq, Wk, Wv, wt);
    hipLaunchKernelGGL(qkv_gemm_kernel,    dim3(32, 24),    dim3(256), 0, stream, xb, wt, qb, kb, vT);
    hipLaunchKernelGGL(attn_kernel,        dim3(768),       dim3(256), 0, stream, qb, kb, vT, out);
}

// Round 5
// 118.788 us; speedup vs baseline: 1.6755x; 1.0502x over previous
//
#include <hip/hip_runtime.h>
#include <hip/hip_bf16.h>

#define NB 4
#define SS 1024
#define DIN 768
#define NH 12
#define DH 64

typedef float f32x4 __attribute__((ext_vector_type(4)));
typedef short bf16x8 __attribute__((ext_vector_type(8)));

static __device__ __forceinline__ unsigned short f2bf(float f) {
    __hip_bfloat16 h = __float2bfloat16(f);
    return *reinterpret_cast<unsigned short*>(&h);
}

static __device__ __forceinline__ float exp2_fast(float x) {
    return __builtin_amdgcn_exp2f(x);   // v_exp_f32: 2^x
}

static __device__ __forceinline__ void gload16(const void* g, void* l) {
    __builtin_amdgcn_global_load_lds(
        (const __attribute__((address_space(1))) void*)g,
        (__attribute__((address_space(3))) void*)l, 16, 0, 0);
}

// ---------------- kernel 1: cast x (f32) -> xb (bf16), [4096][768] ----------------
__global__ void cast_x_kernel(const float* __restrict__ x, unsigned short* __restrict__ xb) {
    int i = (blockIdx.x * 256 + threadIdx.x) * 4;
    float4 v = *reinterpret_cast<const float4*>(x + i);
    ushort4 o;
    o.x = f2bf(v.x); o.y = f2bf(v.y); o.z = f2bf(v.z); o.w = f2bf(v.w);
    *reinterpret_cast<ushort4*>(xb + i) = o;
}

// ------------- kernel 2: W [H][DIN][DH] f32 -> wt [3][H][DH][DIN] bf16 -------------
__global__ void transpose_w_kernel(const float* __restrict__ Wq, const float* __restrict__ Wk,
                                   const float* __restrict__ Wv, unsigned short* __restrict__ wt) {
    __shared__ float lds[64][68];
    int d0 = blockIdx.x * 64;
    int h  = blockIdx.y;
    int p  = blockIdx.z;
    const float* W = (p == 0) ? Wq : (p == 1) ? Wk : Wv;
    const float* base = W + (size_t)h * DIN * DH;   // [768][64]
    int tid = threadIdx.x;
    int rr = tid >> 4, c4 = tid & 15;
#pragma unroll
    for (int i = 0; i < 4; ++i) {
        int d = i * 16 + rr;
        float4 v = *reinterpret_cast<const float4*>(base + (size_t)(d0 + d) * DH + c4 * 4);
        lds[d][c4 * 4 + 0] = v.x; lds[d][c4 * 4 + 1] = v.y;
        lds[d][c4 * 4 + 2] = v.z; lds[d][c4 * 4 + 3] = v.w;
    }
    __syncthreads();
    unsigned short* outp = wt + ((size_t)(p * NH + h) * DH) * DIN;
#pragma unroll
    for (int i = 0; i < 4; ++i) {
        int e = i * 16 + rr;
        int dc = c4 * 4;
        ushort4 o;
        o.x = f2bf(lds[dc + 0][e]); o.y = f2bf(lds[dc + 1][e]);
        o.z = f2bf(lds[dc + 2][e]); o.w = f2bf(lds[dc + 3][e]);
        *reinterpret_cast<ushort4*>(outp + (size_t)e * DIN + d0 + dc) = o;
    }
}

// ---- kernel 3: QKV GEMM. A = xb [4096][768], B^T = wt [2304][768]. Tile 128x96
// ---- (grid 32x24 = 768 blocks = 3/CU exact). gload_lds w16 with pre-swizzled
// ---- source (T2/m173: XOR byte ^ ((row&7)<<4)), swizzled ds_read -> 2-way max.
__global__ __launch_bounds__(256) void qkv_gemm_kernel(
    const unsigned short* __restrict__ xb, const unsigned short* __restrict__ wt,
    unsigned short* __restrict__ qb, unsigned short* __restrict__ kb,
    unsigned short* __restrict__ vT) {
    __shared__ __align__(16) unsigned char smem[28672];
    unsigned short* a_lds = (unsigned short*)smem;            // [128][64] swizzled
    unsigned short* b_lds = (unsigned short*)(smem + 16384);  // [96][64]  swizzled

    int m0 = blockIdx.x * 128;
    int n0 = blockIdx.y * 96;
    int tid = threadIdx.x, lane = tid & 63, w = tid >> 6;
    int l15 = lane & 15, hi4 = (lane >> 4) * 4, hi8 = (lane >> 4) * 8;
    int wr = w >> 1, wc = w & 1;
    int srow = tid >> 3;            // 0..31
    int scolb = (tid & 7) * 16;     // byte col {0,16,...,112}
    int sw = (l15 & 7) << 4;        // read-side XOR

    f32x4 acc[4][3] = {};

    for (int k0 = 0; k0 < DIN; k0 += 64) {
        __syncthreads();
#pragma unroll
        for (int i = 0; i < 4; ++i) {
            int row = i * 32 + srow;
            int cb = scolb ^ ((row & 7) << 4);
            gload16(xb + (size_t)(m0 + row) * DIN + k0 + (cb >> 1), a_lds + row * 64 + (scolb >> 1));
        }
#pragma unroll
        for (int i = 0; i < 3; ++i) {
            int row = i * 32 + srow;
            int cb = scolb ^ ((row & 7) << 4);
            gload16(wt + (size_t)(n0 + row) * DIN + k0 + (cb >> 1), b_lds + row * 64 + (scolb >> 1));
        }
        __syncthreads();
#pragma unroll
        for (int kk = 0; kk < 64; kk += 32) {
            int cb = ((kk + hi8) * 2) ^ sw;
            bf16x8 af[4], bfr[3];
#pragma unroll
            for (int m = 0; m < 4; ++m)
                af[m] = *reinterpret_cast<const bf16x8*>(a_lds + (wr * 64 + m * 16 + l15) * 64 + (cb >> 1));
#pragma unroll
            for (int n = 0; n < 3; ++n)
                bfr[n] = *reinterpret_cast<const bf16x8*>(b_lds + (wc * 48 + n * 16 + l15) * 64 + (cb >> 1));
#pragma unroll
            for (int m = 0; m < 4; ++m)
#pragma unroll
                for (int n = 0; n < 3; ++n)
                    acc[m][n] = __builtin_amdgcn_mfma_f32_16x16x32_bf16(af[m], bfr[n], acc[m][n], 0, 0, 0);
        }
    }
    __syncthreads();   // before LDS scratch reuse

    int p  = n0 / 768;
    int cp = (n0 % 768) + wc * 48;         // col base within projection
    int b  = m0 >> 10;
    int s_base = (m0 & 1023) + wr * 64;

    if (p < 2) {
        float qs = (p == 0) ? 0.180336880f : 1.0f;   // 0.125 * log2(e) folded into Q
        unsigned short* dstb = (p == 0) ? qb : kb;
#pragma unroll
        for (int m = 0; m < 4; ++m)
#pragma unroll
            for (int n = 0; n < 3; ++n)
#pragma unroll
                for (int r = 0; r < 4; ++r) {
                    int col = cp + n * 16 + l15;
                    int h = col >> 6, e = col & 63;
                    dstb[((size_t)(b * NH + h) * SS + s_base + m * 16 + hi4 + r) * DH + e] =
                        f2bf(acc[m][n][r] * qs);
                }
    } else {
        // V: per-wave 16x49 f32 strip transpose, store [b][h][e][t]
        float* sc = (float*)smem + w * 784;
#pragma unroll
        for (int m = 0; m < 4; ++m) {
#pragma unroll
            for (int n = 0; n < 3; ++n)
#pragma unroll
                for (int r = 0; r < 4; ++r)
                    sc[(hi4 + r) * 49 + n * 16 + l15] = acc[m][n][r];
            if (lane < 48) {
                unsigned short vv[16];
#pragma unroll
                for (int t = 0; t < 16; ++t) vv[t] = f2bf(sc[t * 49 + lane]);
                int col = cp + lane;
                int h = col >> 6, e = col & 63;
                unsigned short* dst = vT + ((size_t)(b * NH + h) * DH + e) * SS + s_base + m * 16;
                *reinterpret_cast<uint4*>(dst)     = *reinterpret_cast<const uint4*>(vv);
                *reinterpret_cast<uint4*>(dst + 8) = *reinterpret_cast<const uint4*>(vv + 8);
            }
        }
    }
}

// ---- kernel 4: causal flash attention, swapped-operand (P^T) softmax-in-lane.
// smem layout (bytes): [0,8192) k0 | [8192,16384) k1 | [16384,24576) v0 |
//                      [24576,32768) v1 | [32768,41984) p^T (4 waves x 1152 shorts)
// epilogue reuses [0,17408) as 4 x [16][68] f32 strips.
struct AttnCtx {
    const unsigned short* kg;
    const unsigned short* vg;
    char* smem;
    unsigned short* pw;
    int srow, scolb, l15, hi, sw;
};

static __device__ __forceinline__ void attn_stage(const AttnCtx& c, int buf, int kv) {
    unsigned short* kl = (unsigned short*)(c.smem + buf * 8192);
    unsigned short* vl = (unsigned short*)(c.smem + 16384 + buf * 8192);
#pragma unroll
    for (int i = 0; i < 2; ++i) {
        int row = i * 32 + c.srow;
        int cb = c.scolb ^ ((row & 7) << 4);
        gload16(c.kg + (size_t)(kv * 64 + row) * DH + (cb >> 1), kl + row * 64 + (c.scolb >> 1));
        gload16(c.vg + (size_t)row * SS + kv * 64 + (cb >> 1),   vl + row * 64 + (c.scolb >> 1));
    }
}

template<bool DIAG>
static __device__ __forceinline__ void attn_step(
    const AttnCtx& c, int buf, int kv, int qg,
    bf16x8 qf0, bf16x8 qf1, float& m_r, float& l_r, f32x4 o_acc[4]) {
    const unsigned short* kl = (const unsigned short*)(c.smem + buf * 8192);
    const unsigned short* vl = (const unsigned short*)(c.smem + 16384 + buf * 8192);
    int l15 = c.l15, hi = c.hi, sw = c.sw;
    int hi4 = hi * 4, hi8 = hi * 8;

    // QK^T swapped: sacc[n] = C[kv_local = 16n+hi4+r][q = l15]
    f32x4 sacc[4] = {};
    __builtin_amdgcn_s_setprio(1);
#pragma unroll
    for (int s = 0; s < 2; ++s) {
        int cb = ((32 * s + hi8) * 2) ^ sw;
#pragma unroll
        for (int n = 0; n < 4; ++n) {
            bf16x8 kf = *reinterpret_cast<const bf16x8*>(kl + (16 * n + l15) * 64 + (cb >> 1));
            sacc[n] = __builtin_amdgcn_mfma_f32_16x16x32_bf16(kf, s == 0 ? qf0 : qf1, sacc[n], 0, 0, 0);
        }
    }
    __builtin_amdgcn_s_setprio(0);

    float pv[4][4];
#pragma unroll
    for (int n = 0; n < 4; ++n)
#pragma unroll
        for (int r = 0; r < 4; ++r) {
            float sv = sacc[n][r];
            if (DIAG && (kv * 64 + 16 * n + hi4 + r) > qg) sv = -INFINITY;
            pv[n][r] = sv;
        }

    // in-lane row softmax (this lane owns q = qg's kv-slice; cross-hi via 2 shfl)
    float mn[4];
#pragma unroll
    for (int n = 0; n < 4; ++n)
        mn[n] = fmaxf(fmaxf(pv[n][0], pv[n][1]), fmaxf(pv[n][2], pv[n][3]));
    float mx = fmaxf(fmaxf(mn[0], mn[1]), fmaxf(mn[2], mn[3]));
    mx = fmaxf(mx, __shfl_xor(mx, 16));
    mx = fmaxf(mx, __shfl_xor(mx, 32));

    // defer-max (T13): only rescale when max grew by > 8 (exp2-space, bounded 256)
    if (!__all(mx - m_r <= 8.0f)) {
        float m_new = fmaxf(m_r, mx);
        float alpha = exp2_fast(m_r - m_new);
        l_r *= alpha;
#pragma unroll
        for (int n = 0; n < 4; ++n)
#pragma unroll
            for (int r = 0; r < 4; ++r) o_acc[n][r] *= alpha;
        m_r = m_new;
    }
    float sn[4];
#pragma unroll
    for (int n = 0; n < 4; ++n) {
#pragma unroll
        for (int r = 0; r < 4; ++r) pv[n][r] = exp2_fast(pv[n][r] - m_r);
        sn[n] = (pv[n][0] + pv[n][1]) + (pv[n][2] + pv[n][3]);
    }
    float sum = (sn[0] + sn[1]) + (sn[2] + sn[3]);
    sum += __shfl_xor(sum, 16);
    sum += __shfl_xor(sum, 32);
    l_r += sum;

    // P^T -> bf16 packed b32 writes: pw[q = l15][kv = 16n+hi4+{0..3}]
    unsigned int* pwu = (unsigned int*)c.pw;
#pragma unroll
    for (int n = 0; n < 4; ++n)
#pragma unroll
        for (int p2 = 0; p2 < 2; ++p2) {
            unsigned int w32 = (unsigned int)f2bf(pv[n][2 * p2]) |
                               ((unsigned int)f2bf(pv[n][2 * p2 + 1]) << 16);
            pwu[l15 * 36 + 8 * n + 2 * hi + p2] = w32;
        }
    bf16x8 pa0 = *reinterpret_cast<const bf16x8*>(c.pw + l15 * 72 + hi8);
    bf16x8 pa1 = *reinterpret_cast<const bf16x8*>(c.pw + l15 * 72 + 32 + hi8);

    // O^T += V^T . P^T : o_acc[n] = C[e = 16n+hi4+r][q = l15]
    __builtin_amdgcn_s_setprio(1);
#pragma unroll
    for (int s = 0; s < 2; ++s) {
        int cb = ((32 * s + hi8) * 2) ^ sw;
#pragma unroll
        for (int n = 0; n < 4; ++n) {
            bf16x8 vf = *reinterpret_cast<const bf16x8*>(vl + (16 * n + l15) * 64 + (cb >> 1));
            o_acc[n] = __builtin_amdgcn_mfma_f32_16x16x32_bf16(vf, s == 0 ? pa0 : pa1, o_acc[n], 0, 0, 0);
        }
    }
    __builtin_amdgcn_s_setprio(0);
}

__global__ __launch_bounds__(256) void attn_kernel(
    const unsigned short* __restrict__ qb, const unsigned short* __restrict__ kb,
    const unsigned short* __restrict__ vT, float* __restrict__ out) {
    __shared__ __align__(16) char smem[41984];

    // load-balanced decode: long blocks (qi=15) first
    int bid = blockIdx.x;
    int qi = 15 - bid / 48;
    int rem = bid % 48;
    int h = rem % 12, b = rem / 12;
    int q0 = qi * 64;
    int tid = threadIdx.x, lane = tid & 63, w = tid >> 6;
    int l15 = lane & 15, hi = lane >> 4;
    size_t bh = (size_t)(b * NH + h);

    AttnCtx c;
    c.kg = kb + bh * SS * DH;
    c.vg = vT + bh * DH * SS;
    c.smem = smem;
    c.pw = (unsigned short*)(smem + 32768) + w * 1152;
    c.srow = tid >> 3; c.scolb = (tid & 7) * 16;
    c.l15 = l15; c.hi = hi; c.sw = (l15 & 7) << 4;

    int qg = q0 + 16 * w + l15;
    const unsigned short* qp = qb + (bh * SS + qg) * DH;
    bf16x8 qf0 = *reinterpret_cast<const bf16x8*>(qp + hi * 8);
    bf16x8 qf1 = *reinterpret_cast<const bf16x8*>(qp + 32 + hi * 8);

    float m_r = -INFINITY, l_r = 0.f;
    f32x4 o_acc[4] = {};

    attn_stage(c, 0, 0);
    __syncthreads();
    for (int kv = 0; kv < qi; ++kv) {
        attn_stage(c, (kv & 1) ^ 1, kv + 1);       // overlap next-tile DMA with compute
        attn_step<false>(c, kv & 1, kv, qg, qf0, qf1, m_r, l_r, o_acc);
        __syncthreads();
    }
    attn_step<true>(c, qi & 1, qi, qg, qf0, qf1, m_r, l_r, o_acc);
    __syncthreads();   // before LDS scratch reuse

    // epilogue: O^T -> LDS strip -> coalesced float4 stores
    float inv = 1.f / l_r;
    float* sc = (float*)(smem + w * 4352);         // [16 q][68 e]
#pragma unroll
    for (int n = 0; n < 4; ++n)
#pragma unroll
        for (int r = 0; r < 4; ++r)
            sc[l15 * 68 + 16 * n + hi * 4 + r] = o_acc[n][r] * inv;
    __builtin_amdgcn_s_waitcnt(0);                 // lgkm drain (wave-private strip)
#pragma unroll
    for (int j = 0; j < 4; ++j) {
        f32x4 v = *reinterpret_cast<const f32x4*>(sc + l15 * 68 + j * 16 + hi * 4);
        *reinterpret_cast<f32x4*>(out + ((size_t)b * SS + q0 + 16 * w + l15) * (NH * DH)
                                  + h * DH + j * 16 + hi * 4) = v;
    }
}

extern "C" void kernel_launch(void* const* d_in, const int* in_sizes, int n_in,
                              void* d_out, int out_size, void* d_ws, size_t ws_size,
                              hipStream_t stream) {
    const float* x  = (const float*)d_in[0];
    const float* Wq = (const float*)d_in[1];
    const float* Wk = (const float*)d_in[2];
    const float* Wv = (const float*)d_in[3];
    float* out = (float*)d_out;

    char* ws = (char*)d_ws;
    unsigned short* xb = (unsigned short*)ws;                   //  6,291,456 B
    unsigned short* wt = (unsigned short*)(ws +  6291456);      //  3,538,944 B
    unsigned short* qb = (unsigned short*)(ws +  9830400);      //  6,291,456 B
    unsigned short* kb = (unsigned short*)(ws + 16121856);      //  6,291,456 B
    unsigned short* vT = (unsigned short*)(ws + 22413312);      //  6,291,456 B

    hipLaunchKernelGGL(cast_x_kernel,      dim3(3072),      dim3(256), 0, stream, x, xb);
    hipLaunchKernelGGL(transpose_w_kernel, dim3(12, 12, 3), dim3(256), 0, stream, Wq, Wk, Wv, wt);
    hipLaunchKernelGGL(qkv_gemm_kernel,    dim3(32, 24),    dim3(256), 0, stream, xb, wt, qb, kb, vT);
    hipLaunchKernelGGL(attn_kernel,        dim3(768),       dim3(256), 0, stream, qb, kb, vT, out);
}

// Round 7
// 116.178 us; speedup vs baseline: 1.7132x; 1.0225x over previous
//
#include <hip/hip_runtime.h>
#include <hip/hip_bf16.h>

#define NB 4
#define SS 1024
#define DIN 768
#define NH 12
#define DH 64

typedef float f32x4 __attribute__((ext_vector_type(4)));
typedef short bf16x8 __attribute__((ext_vector_type(8)));

static __device__ __forceinline__ unsigned short f2bf(float f) {
    __hip_bfloat16 h = __float2bfloat16(f);
    return *reinterpret_cast<unsigned short*>(&h);
}

static __device__ __forceinline__ float exp2_fast(float x) {
    return __builtin_amdgcn_exp2f(x);   // v_exp_f32: 2^x
}

static __device__ __forceinline__ void gload16(const void* g, void* l) {
    __builtin_amdgcn_global_load_lds(
        (const __attribute__((address_space(1))) void*)g,
        (__attribute__((address_space(3))) void*)l, 16, 0, 0);
}

// ---------- kernel 1: prep = cast x -> bf16  +  transpose W -> wt (fused) ----------
__global__ void prep_kernel(const float* __restrict__ x, const float* __restrict__ Wq,
                            const float* __restrict__ Wk, const float* __restrict__ Wv,
                            unsigned short* __restrict__ xb, unsigned short* __restrict__ wt) {
    __shared__ float lds[64][68];
    int bid = blockIdx.x, tid = threadIdx.x;
    {
        int i = (bid * 256 + tid) * 4;
        float4 v = *reinterpret_cast<const float4*>(x + i);
        ushort4 o;
        o.x = f2bf(v.x); o.y = f2bf(v.y); o.z = f2bf(v.z); o.w = f2bf(v.w);
        *reinterpret_cast<ushort4*>(xb + i) = o;
    }
    if (bid < 432) {
        int d0 = (bid % 12) * 64, h = (bid / 12) % 12, p = bid / 144;
        const float* W = (p == 0) ? Wq : (p == 1) ? Wk : Wv;
        const float* base = W + (size_t)h * DIN * DH;   // [768][64]
        int rr = tid >> 4, c4 = tid & 15;
#pragma unroll
        for (int i = 0; i < 4; ++i) {
            int d = i * 16 + rr;
            float4 v = *reinterpret_cast<const float4*>(base + (size_t)(d0 + d) * DH + c4 * 4);
            lds[d][c4 * 4 + 0] = v.x; lds[d][c4 * 4 + 1] = v.y;
            lds[d][c4 * 4 + 2] = v.z; lds[d][c4 * 4 + 3] = v.w;
        }
        __syncthreads();
        unsigned short* outp = wt + ((size_t)(p * NH + h) * DH) * DIN;
#pragma unroll
        for (int i = 0; i < 4; ++i) {
            int e = i * 16 + rr;
            int dc = c4 * 4;
            ushort4 o;
            o.x = f2bf(lds[dc + 0][e]); o.y = f2bf(lds[dc + 1][e]);
            o.z = f2bf(lds[dc + 2][e]); o.w = f2bf(lds[dc + 3][e]);
            *reinterpret_cast<ushort4*>(outp + (size_t)e * DIN + d0 + dc) = o;
        }
    }
}

// ---- kernel 2: QKV GEMM. A = xb [4096][768], B^T = wt [2304][768]. Tile 128x96,
// ---- 1D grid 768 with XCD-aware swizzle (768%8==0). gload_lds w16, T2 swizzle.
__global__ __launch_bounds__(256) void qkv_gemm_kernel(
    const unsigned short* __restrict__ xb, const unsigned short* __restrict__ wt,
    unsigned short* __restrict__ qb, unsigned short* __restrict__ kb,
    unsigned short* __restrict__ vT) {
    __shared__ __align__(16) unsigned char smem[28672];
    unsigned short* a_lds = (unsigned short*)smem;            // [128][64] swizzled
    unsigned short* b_lds = (unsigned short*)(smem + 16384);  // [96][64]  swizzled

    // XCD swizzle: contiguous 96-block chunk per XCD -> 3 B-panels/XCD in L2
    int sb = (blockIdx.x & 7) * 96 + (blockIdx.x >> 3);
    int m0 = (sb & 31) * 128;
    int n0 = (sb >> 5) * 96;
    int tid = threadIdx.x, lane = tid & 63, w = tid >> 6;
    int l15 = lane & 15, hi4 = (lane >> 4) * 4, hi8 = (lane >> 4) * 8;
    int wr = w >> 1, wc = w & 1;
    int srow = tid >> 3;            // 0..31
    int scolb = (tid & 7) * 16;     // byte col
    int sw = (l15 & 7) << 4;        // read-side XOR

    f32x4 acc[4][3] = {};

    for (int k0 = 0; k0 < DIN; k0 += 64) {
        __syncthreads();
#pragma unroll
        for (int i = 0; i < 4; ++i) {
            int row = i * 32 + srow;
            int cb = scolb ^ ((row & 7) << 4);
            gload16(xb + (size_t)(m0 + row) * DIN + k0 + (cb >> 1), a_lds + row * 64 + (scolb >> 1));
        }
#pragma unroll
        for (int i = 0; i < 3; ++i) {
            int row = i * 32 + srow;
            int cb = scolb ^ ((row & 7) << 4);
            gload16(wt + (size_t)(n0 + row) * DIN + k0 + (cb >> 1), b_lds + row * 64 + (scolb >> 1));
        }
        __syncthreads();
#pragma unroll
        for (int kk = 0; kk < 64; kk += 32) {
            int cb = ((kk + hi8) * 2) ^ sw;
            bf16x8 af[4], bfr[3];
#pragma unroll
            for (int m = 0; m < 4; ++m)
                af[m] = *reinterpret_cast<const bf16x8*>(a_lds + (wr * 64 + m * 16 + l15) * 64 + (cb >> 1));
#pragma unroll
            for (int n = 0; n < 3; ++n)
                bfr[n] = *reinterpret_cast<const bf16x8*>(b_lds + (wc * 48 + n * 16 + l15) * 64 + (cb >> 1));
#pragma unroll
            for (int m = 0; m < 4; ++m)
#pragma unroll
                for (int n = 0; n < 3; ++n)
                    acc[m][n] = __builtin_amdgcn_mfma_f32_16x16x32_bf16(af[m], bfr[n], acc[m][n], 0, 0, 0);
        }
    }
    __syncthreads();   // before LDS scratch reuse

    int p  = n0 / 768;
    int cp = (n0 % 768) + wc * 48;
    int b  = m0 >> 10;
    int s_base = (m0 & 1023) + wr * 64;

    if (p < 2) {
        float qs = (p == 0) ? 0.180336880f : 1.0f;   // 0.125*log2(e) folded into Q
        unsigned short* dstb = (p == 0) ? qb : kb;
#pragma unroll
        for (int m = 0; m < 4; ++m)
#pragma unroll
            for (int n = 0; n < 3; ++n)
#pragma unroll
                for (int r = 0; r < 4; ++r) {
                    int col = cp + n * 16 + l15;
                    int h = col >> 6, e = col & 63;
                    dstb[((size_t)(b * NH + h) * SS + s_base + m * 16 + hi4 + r) * DH + e] =
                        f2bf(acc[m][n][r] * qs);
                }
    } else {
        // V: per-wave 16x49 f32 strip transpose, store [b][h][e][t]
        float* sc = (float*)smem + w * 784;
#pragma unroll
        for (int m = 0; m < 4; ++m) {
#pragma unroll
            for (int n = 0; n < 3; ++n)
#pragma unroll
                for (int r = 0; r < 4; ++r)
                    sc[(hi4 + r) * 49 + n * 16 + l15] = acc[m][n][r];
            if (lane < 48) {
                unsigned short vv[16];
#pragma unroll
                for (int t2 = 0; t2 < 16; ++t2) vv[t2] = f2bf(sc[t2 * 49 + lane]);
                int col = cp + lane;
                int h = col >> 6, e = col & 63;
                unsigned short* dst = vT + ((size_t)(b * NH + h) * DH + e) * SS + s_base + m * 16;
                *reinterpret_cast<uint4*>(dst)     = *reinterpret_cast<const uint4*>(vv);
                *reinterpret_cast<uint4*>(dst + 8) = *reinterpret_cast<const uint4*>(vv + 8);
            }
        }
    }
}

// ---- kernel 3: causal flash attention, swapped-operand softmax-in-lane.
// LDS = 40960 B exactly -> 4 blocks/CU:
//   [0,8192) k0 | [8192,16384) k1 | [16384,24576) v0 | [24576,32768) v1
//   [32768,40960) P^T: per-wave 2048 B, rows q=l15 (stride 64 shorts), XOR-swizzled
struct AttnCtx {
    const unsigned short* kg;
    const unsigned short* vg;
    char* smem;
    unsigned short* pw;
    int srow, scolb, l15, hi, sw;
};

static __device__ __forceinline__ void attn_stage(const AttnCtx& c, int buf, int kv) {
    unsigned short* kl = (unsigned short*)(c.smem + buf * 8192);
    unsigned short* vl = (unsigned short*)(c.smem + 16384 + buf * 8192);
#pragma unroll
    for (int i = 0; i < 2; ++i) {
        int row = i * 32 + c.srow;
        int cb = c.scolb ^ ((row & 7) << 4);
        gload16(c.kg + (size_t)(kv * 64 + row) * DH + (cb >> 1), kl + row * 64 + (c.scolb >> 1));
        gload16(c.vg + (size_t)row * SS + kv * 64 + (cb >> 1),   vl + row * 64 + (c.scolb >> 1));
    }
}

template<bool DIAG>
static __device__ __forceinline__ void attn_step(
    const AttnCtx& c, int buf, int kv, int qg,
    bf16x8 qf0, bf16x8 qf1, float& m_r, float& l_r, f32x4 o_acc[4]) {
    const unsigned short* kl = (const unsigned short*)(c.smem + buf * 8192);
    const unsigned short* vl = (const unsigned short*)(c.smem + 16384 + buf * 8192);
    int l15 = c.l15, hi = c.hi, sw = c.sw;
    int hi4 = hi * 4, hi8 = hi * 8;

    // QK^T swapped: sacc[n] = C[kv_local = 16n+hi4+r][q = l15]
    f32x4 sacc[4] = {};
    __builtin_amdgcn_s_setprio(1);
#pragma unroll
    for (int s = 0; s < 2; ++s) {
        int cb = ((32 * s + hi8) * 2) ^ sw;
#pragma unroll
        for (int n = 0; n < 4; ++n) {
            bf16x8 kf = *reinterpret_cast<const bf16x8*>(kl + (16 * n + l15) * 64 + (cb >> 1));
            sacc[n] = __builtin_amdgcn_mfma_f32_16x16x32_bf16(kf, s == 0 ? qf0 : qf1, sacc[n], 0, 0, 0);
        }
    }
    __builtin_amdgcn_s_setprio(0);

    float pv[4][4];
#pragma unroll
    for (int n = 0; n < 4; ++n)
#pragma unroll
        for (int r = 0; r < 4; ++r) {
            float sv = sacc[n][r];
            if (DIAG && (kv * 64 + 16 * n + hi4 + r) > qg) sv = -INFINITY;
            pv[n][r] = sv;
        }

    // in-lane row softmax (lane owns q = qg; cross-hi via 2 shfl)
    float mn[4];
#pragma unroll
    for (int n = 0; n < 4; ++n)
        mn[n] = fmaxf(fmaxf(pv[n][0], pv[n][1]), fmaxf(pv[n][2], pv[n][3]));
    float mx = fmaxf(fmaxf(mn[0], mn[1]), fmaxf(mn[2], mn[3]));
    mx = fmaxf(mx, __shfl_xor(mx, 16));
    mx = fmaxf(mx, __shfl_xor(mx, 32));

    // defer-max (T13)
    if (!__all(mx - m_r <= 8.0f)) {
        float m_new = fmaxf(m_r, mx);
        float alpha = exp2_fast(m_r - m_new);
        l_r *= alpha;
#pragma unroll
        for (int n = 0; n < 4; ++n)
#pragma unroll
            for (int r = 0; r < 4; ++r) o_acc[n][r] *= alpha;
        m_r = m_new;
    }
    float sn[4];
#pragma unroll
    for (int n = 0; n < 4; ++n) {
#pragma unroll
        for (int r = 0; r < 4; ++r) pv[n][r] = exp2_fast(pv[n][r] - m_r);
        sn[n] = (pv[n][0] + pv[n][1]) + (pv[n][2] + pv[n][3]);
    }
    float sum = (sn[0] + sn[1]) + (sn[2] + sn[3]);
    sum += __shfl_xor(sum, 16);
    sum += __shfl_xor(sum, 32);
    l_r += sum;

    // P^T -> swizzled stride-64 LDS (row q=l15, u32 idx (8n+2hi+p2)^xr)
    int xr = (l15 & 7) * 4;
    unsigned int* pwu = (unsigned int*)c.pw;
#pragma unroll
    for (int n = 0; n < 4; ++n)
#pragma unroll
        for (int p2 = 0; p2 < 2; ++p2) {
            unsigned int w32 = (unsigned int)f2bf(pv[n][2 * p2]) |
                               ((unsigned int)f2bf(pv[n][2 * p2 + 1]) << 16);
            pwu[l15 * 32 + ((8 * n + 2 * hi + p2) ^ xr)] = w32;
        }
    int i0 = (4 * hi) ^ xr;          // u32 base for kv 8hi..8hi+7
    int i1 = (16 + 4 * hi) ^ xr;     // u32 base for kv 32+8hi..32+8hi+7
    bf16x8 pa0 = *reinterpret_cast<const bf16x8*>(c.pw + l15 * 64 + i0 * 2);
    bf16x8 pa1 = *reinterpret_cast<const bf16x8*>(c.pw + l15 * 64 + i1 * 2);

    // O^T += V^T . P^T : o_acc[n] = C[e = 16n+hi4+r][q = l15]
    __builtin_amdgcn_s_setprio(1);
#pragma unroll
    for (int s = 0; s < 2; ++s) {
        int cb = ((32 * s + hi8) * 2) ^ sw;
#pragma unroll
        for (int n = 0; n < 4; ++n) {
            bf16x8 vf = *reinterpret_cast<const bf16x8*>(vl + (16 * n + l15) * 64 + (cb >> 1));
            o_acc[n] = __builtin_amdgcn_mfma_f32_16x16x32_bf16(vf, s == 0 ? pa0 : pa1, o_acc[n], 0, 0, 0);
        }
    }
    __builtin_amdgcn_s_setprio(0);
}

__global__ __launch_bounds__(256, 4) void attn_kernel(
    const unsigned short* __restrict__ qb, const unsigned short* __restrict__ kb,
    const unsigned short* __restrict__ vT, float* __restrict__ out) {
    __shared__ __align__(16) char smem[40960];

    // load-balanced decode: long blocks (qi=15) first; all tiles of a (b,h)
    // share bid%8 -> same XCD L2 for K/V panels
    int bid = blockIdx.x;
    int qi = 15 - bid / 48;
    int rem = bid % 48;
    int h = rem % 12, b = rem / 12;
    int q0 = qi * 64;
    int tid = threadIdx.x, lane = tid & 63, w = tid >> 6;
    int l15 = lane & 15, hi = lane >> 4;
    int hi4 = hi * 4, hi8 = hi * 8;
    size_t bh = (size_t)(b * NH + h);

    AttnCtx c;
    c.kg = kb + bh * SS * DH;
    c.vg = vT + bh * DH * SS;
    c.smem = smem;
    c.pw = (unsigned short*)(smem + 32768) + w * 1024;
    c.srow = tid >> 3; c.scolb = (tid & 7) * 16;
    c.l15 = l15; c.hi = hi; c.sw = (l15 & 7) << 4;

    int qg = q0 + 16 * w + l15;
    const unsigned short* qp = qb + (bh * SS + qg) * DH;
    bf16x8 qf0 = *reinterpret_cast<const bf16x8*>(qp + hi8);
    bf16x8 qf1 = *reinterpret_cast<const bf16x8*>(qp + 32 + hi8);

    float m_r = -INFINITY, l_r = 0.f;
    f32x4 o_acc[4] = {};

    attn_stage(c, 0, 0);
    __syncthreads();
    for (int kv = 0; kv < qi; ++kv) {
        attn_stage(c, (kv & 1) ^ 1, kv + 1);       // overlap next-tile DMA with compute
        attn_step<false>(c, kv & 1, kv, qg, qf0, qf1, m_r, l_r, o_acc);
        __syncthreads();
    }
    attn_step<true>(c, qi & 1, qi, qg, qf0, qf1, m_r, l_r, o_acc);
    __syncthreads();   // before LDS scratch reuse

    // epilogue: O^T -> per-wave LDS strip -> coalesced float4 stores
    float inv = 1.f / l_r;
    float* sc = (float*)(smem + w * 4352);         // [16 q][68 e]
#pragma unroll
    for (int n = 0; n < 4; ++n)
#pragma unroll
        for (int r = 0; r < 4; ++r)
            sc[l15 * 68 + 16 * n + hi4 + r] = o_acc[n][r] * inv;
    __builtin_amdgcn_s_waitcnt(0);                 // lgkm drain (wave-private strip)
#pragma unroll
    for (int j = 0; j < 4; ++j) {
        f32x4 v = *reinterpret_cast<const f32x4*>(sc + l15 * 68 + j * 16 + hi4);
        *reinterpret_cast<f32x4*>(out + ((size_t)b * SS + q0 + 16 * w + l15) * (NH * DH)
                                  + h * DH + j * 16 + hi4) = v;
    }
}

extern "C" void kernel_launch(void* const* d_in, const int* in_sizes, int n_in,
                              void* d_out, int out_size, void* d_ws, size_t ws_size,
                              hipStream_t stream) {
    const float* x  = (const float*)d_in[0];
    const float* Wq = (const float*)d_in[1];
    const float* Wk = (const float*)d_in[2];
    const float* Wv = (const float*)d_in[3];
    float* out = (float*)d_out;

    char* ws = (char*)d_ws;
    unsigned short* xb = (unsigned short*)ws;                   //  6,291,456 B
    unsigned short* wt = (unsigned short*)(ws +  6291456);      //  3,538,944 B
    unsigned short* qb = (unsigned short*)(ws +  9830400);      //  6,291,456 B
    unsigned short* kb = (unsigned short*)(ws + 16121856);      //  6,291,456 B
    unsigned short* vT = (unsigned short*)(ws + 22413312);      //  6,291,456 B

    hipLaunchKernelGGL(prep_kernel,     dim3(3072), dim3(256), 0, stream, x, Wq, Wk, Wv, xb, wt);
    hipLaunchKernelGGL(qkv_gemm_kernel, dim3(768),  dim3(256), 0, stream, xb, wt, qb, kb, vT);
    hipLaunchKernelGGL(attn_kernel,     dim3(768),  dim3(256), 0, stream, qb, kb, vT, out);
}